// Round 2
// baseline (623.300 us; speedup 1.0000x reference)
//
#include <hip/hip_runtime.h>
#include <cstdint>
#include <cstddef>

#define BATCH 4
#define CCH   256
#define HW    4096
#define NM    4096

typedef __attribute__((ext_vector_type(8))) short s16x8;
typedef __attribute__((ext_vector_type(4))) float f32x4;

__device__ __forceinline__ short f2bf(float f) {
    unsigned u = __float_as_uint(f);
    u += 0x7FFFu + ((u >> 16) & 1u);
    return (short)(u >> 16);
}
__device__ __forceinline__ float bf2f(short s) {
    return __uint_as_float(((unsigned)(unsigned short)s) << 16);
}

// ---------------------------------------------------------------------------
// k_cast: fp32 -> bf16, same layout (weights only).
// ---------------------------------------------------------------------------
__global__ __launch_bounds__(256) void k_cast(const float* __restrict__ s,
                                              short* __restrict__ d, int n) {
    int i = (blockIdx.x * 256 + threadIdx.x) * 4;
    if (i + 3 < n) {
        float4 v = *(const float4*)&s[i];
        *(short4*)&d[i] = make_short4(f2bf(v.x), f2bf(v.y), f2bf(v.z), f2bf(v.w));
    }
}

// ---------------------------------------------------------------------------
// k_prep: one pass over in1/in2 producing direct bf16 (b,c,p) and transposed
// bf16 (b,p,c). grid (HW/64, CCH/64, 8): z = b*2+which.
// ---------------------------------------------------------------------------
__global__ __launch_bounds__(256) void k_prep(const float* __restrict__ in1,
                                              const float* __restrict__ in2,
                                              short* __restrict__ X16,
                                              short* __restrict__ Q16,
                                              short* __restrict__ Xt16,
                                              short* __restrict__ Qt16) {
    __shared__ short S[64][72];
    int t = threadIdx.x;
    int p0 = blockIdx.x * 64, c0 = blockIdx.y * 64;
    int z = blockIdx.z;
    int b = z >> 1, which = z & 1;
    const float* src = (which ? in2 : in1) + (size_t)b * CCH * HW;
    short* direct = (which ? Q16 : X16) + (size_t)b * CCH * HW;
    short* trans  = (which ? Qt16 : Xt16) + (size_t)b * HW * CCH;
    int tx = t & 15, ty = t >> 4;
#pragma unroll
    for (int i = 0; i < 4; ++i) {
        int c = ty + i * 16;
        float4 v = *(const float4*)&src[(size_t)(c0 + c) * HW + p0 + tx * 4];
        short4 h = make_short4(f2bf(v.x), f2bf(v.y), f2bf(v.z), f2bf(v.w));
        *(short4*)&direct[(size_t)(c0 + c) * HW + p0 + tx * 4] = h;
        S[tx * 4 + 0][c] = h.x;
        S[tx * 4 + 1][c] = h.y;
        S[tx * 4 + 2][c] = h.z;
        S[tx * 4 + 3][c] = h.w;
    }
    __syncthreads();
#pragma unroll
    for (int i = 0; i < 4; ++i) {
        int p = ty + i * 16;
        short4 v = *(const short4*)&S[p][tx * 4];
        *(short4*)&trans[(size_t)(p0 + p) * CCH + c0 + tx * 4] = v;
    }
}

// ---------------------------------------------------------------------------
// k_E_mfma: E16n[b,n,d] = bf16( sum_c Xt16[b,n,c] * We16[d,c] )
// TM=128(n), TN=128(d), BK=64, K=256. grid (2, 32, B), block 256.
// ---------------------------------------------------------------------------
__global__ __launch_bounds__(256) void k_E_mfma(const short* __restrict__ Xt16,
                                                const short* __restrict__ We16,
                                                short* __restrict__ E16n) {
    __shared__ short As[128 * 72];
    __shared__ short Bs[128 * 72];
    int t = threadIdx.x;
    int d0 = blockIdx.x * 128, n0 = blockIdx.y * 128, b = blockIdx.z;
    const short* Xb = Xt16 + (size_t)b * HW * CCH;
    short* Eb = E16n + (size_t)b * HW * CCH;
    int lm = t & 15, q = (t >> 4) & 3, w = t >> 6;
    int wr = (w >> 1) * 64, wc = (w & 1) * 64;
    f32x4 acc[4][4];
#pragma unroll
    for (int i = 0; i < 4; ++i)
#pragma unroll
        for (int j = 0; j < 4; ++j) acc[i][j] = (f32x4){0.f, 0.f, 0.f, 0.f};

    for (int k0 = 0; k0 < CCH; k0 += 64) {
#pragma unroll
        for (int u = 0; u < 4; ++u) {
            int chunk = t + u * 256;
            int row = chunk >> 3, off = (chunk & 7) * 8;
            *(float4*)&As[row * 72 + off] =
                *(const float4*)&Xb[(size_t)(n0 + row) * CCH + k0 + off];
            *(float4*)&Bs[row * 72 + off] =
                *(const float4*)&We16[(size_t)(d0 + row) * CCH + k0 + off];
        }
        __syncthreads();
#pragma unroll
        for (int kk = 0; kk < 2; ++kk) {
            s16x8 af[4], bfr[4];
#pragma unroll
            for (int i = 0; i < 4; ++i)
                af[i] = *(const s16x8*)&As[(wr + i * 16 + lm) * 72 + kk * 32 + q * 8];
#pragma unroll
            for (int j = 0; j < 4; ++j)
                bfr[j] = *(const s16x8*)&Bs[(wc + j * 16 + lm) * 72 + kk * 32 + q * 8];
#pragma unroll
            for (int i = 0; i < 4; ++i)
#pragma unroll
                for (int j = 0; j < 4; ++j)
                    acc[i][j] = __builtin_amdgcn_mfma_f32_16x16x32_bf16(
                        af[i], bfr[j], acc[i][j], 0, 0, 0);
        }
        __syncthreads();
    }
#pragma unroll
    for (int i = 0; i < 4; ++i)
#pragma unroll
        for (int r = 0; r < 4; ++r) {
            size_t base = (size_t)(n0 + wr + i * 16 + q * 4 + r) * CCH;
#pragma unroll
            for (int j = 0; j < 4; ++j)
                Eb[base + d0 + wc + j * 16 + lm] = f2bf(acc[i][j][r]);
        }
}

// ---------------------------------------------------------------------------
// k_fused v4: 32 rows/block (grid 1024 -> 4 blocks/CU, ~46% occupancy),
// double-buffered Ps (1 barrier per col-tile), setprio around MFMA clusters.
// which=0 (eatt rows n): Ar=E16n, Ac=Qt16, V=Q16, gate->m1v.
// which=1 (qatt rows m): Ar=Qt16, Ac=E16n, V=X16, gate->m2v.
// unit = gid&7 keeps XCD affinity for L2-resident Ac/V (2+2 MB per unit).
// ---------------------------------------------------------------------------
__global__ __launch_bounds__(256, 4) void k_fused(const short* __restrict__ E16n,
                                                  const short* __restrict__ Qt16,
                                                  const short* __restrict__ Q16,
                                                  const short* __restrict__ X16,
                                                  const float* __restrict__ gw,
                                                  short* __restrict__ eattT,
                                                  short* __restrict__ qattT,
                                                  float* __restrict__ m1v,
                                                  float* __restrict__ m2v) {
    __shared__ short ArS[32 * 264];    // 16.9 KB (132 dw stride; mod-32 = 4)
    __shared__ short Ps[2][32 * 136];  // 17.4 KB double-buffered (68 dw stride)
    __shared__ float rs[4 * 32];       // rowsum cross-wave
    __shared__ float grs[4 * 32];      // gate-dot cross-wave

    int t = threadIdx.x;
    int gid = blockIdx.x;
    int unit = gid & 7;
    int b = unit >> 1, which = unit & 1;
    int r0 = (gid >> 3) * 32;

    const short* Ar = (which ? Qt16 : E16n) + (size_t)b * HW * CCH;
    const short* Ac = (which ? E16n : Qt16) + (size_t)b * HW * CCH;
    const short* V  = (which ? X16  : Q16 ) + (size_t)b * CCH * HW;
    short* Out = (which ? qattT : eattT) + (size_t)b * HW * CCH;
    float* mdst = (which ? m2v : m1v) + (size_t)b * HW;

    int lm = t & 15, q = (t >> 4) & 3, w = t >> 6;
    int wqs = w * 32;   // this wave's score-column quarter (of 128)
    int cq  = w * 64;   // this wave's V-channel quarter (of 256)

    // gate weights for this lane's 4 channels
    float gwv[4];
#pragma unroll
    for (int j = 0; j < 4; ++j) gwv[j] = gw[cq + j * 16 + lm];

    // ---- preload Ar rows [r0, r0+32) x K=256 into LDS (once)
#pragma unroll
    for (int u = 0; u < 4; ++u) {
        int chunk = t + u * 256;
        int row = chunk >> 5, off = (chunk & 31) * 8;
        *(float4*)&ArS[row * 264 + off] =
            *(const float4*)&Ar[(size_t)(r0 + row) * CCH + off];
    }
    __syncthreads();

    // register-cache first 2 of 8 k-chunks of the Ar fragments
    s16x8 afc[2][2];
#pragma unroll
    for (int kk = 0; kk < 2; ++kk)
#pragma unroll
        for (int i = 0; i < 2; ++i)
            afc[kk][i] = *(const s16x8*)&ArS[(i * 16 + lm) * 264 + kk * 32 + q * 8];

    f32x4 oacc[2][4];
    float rsum[2][4];
#pragma unroll
    for (int i = 0; i < 2; ++i) {
#pragma unroll
        for (int j = 0; j < 4; ++j) oacc[i][j] = (f32x4){0.f, 0.f, 0.f, 0.f};
#pragma unroll
        for (int r = 0; r < 4; ++r) rsum[i][r] = 0.f;
    }

    int buf = 0;
    for (int col0 = 0; col0 < NM; col0 += 128, buf ^= 1) {
        // ---- score: S[32][128] = Ar . Ac[col0:+128]^T  (barrier-free)
        f32x4 sacc[2][2];
#pragma unroll
        for (int i = 0; i < 2; ++i)
#pragma unroll
            for (int j = 0; j < 2; ++j) sacc[i][j] = (f32x4){0.f, 0.f, 0.f, 0.f};
#pragma unroll
        for (int kk = 0; kk < 8; ++kk) {
            s16x8 af[2], bf[2];
#pragma unroll
            for (int i = 0; i < 2; ++i) {
                if (kk < 2) af[i] = afc[kk][i];
                else af[i] = *(const s16x8*)&ArS[(i * 16 + lm) * 264 + kk * 32 + q * 8];
            }
#pragma unroll
            for (int j = 0; j < 2; ++j)
                bf[j] = *(const s16x8*)&Ac[(size_t)(col0 + wqs + j * 16 + lm) * CCH +
                                           kk * 32 + q * 8];
            __builtin_amdgcn_s_setprio(1);
#pragma unroll
            for (int i = 0; i < 2; ++i)
#pragma unroll
                for (int j = 0; j < 2; ++j)
                    sacc[i][j] = __builtin_amdgcn_mfma_f32_16x16x32_bf16(
                        af[i], bf[j], sacc[i][j], 0, 0, 0);
            __builtin_amdgcn_s_setprio(0);
        }
        // ---- exp in registers (pre-barrier; bf16-rounded value kept in sacc)
#pragma unroll
        for (int i = 0; i < 2; ++i)
#pragma unroll
            for (int j = 0; j < 2; ++j)
#pragma unroll
                for (int r = 0; r < 4; ++r) {
                    float v = bf2f(f2bf(__expf(sacc[i][j][r])));
                    rsum[i][r] += v;
                    sacc[i][j][r] = v;
                }
        // write this tile's P into buffer `buf`; safe without a pre-barrier:
        // all waves' PV reads of Ps[buf] (tile t-2) completed before the
        // barrier of tile t-1, which every wave has passed.
#pragma unroll
        for (int i = 0; i < 2; ++i)
#pragma unroll
            for (int j = 0; j < 2; ++j)
#pragma unroll
                for (int r = 0; r < 4; ++r)
                    Ps[buf][(i * 16 + q * 4 + r) * 136 + wqs + j * 16 + lm] =
                        (short)(__float_as_uint(sacc[i][j][r]) >> 16);
        __syncthreads();   // Ps[buf] visible to all waves
        // ---- PV: oacc += P[:, tile] . V[:, tile]^T
#pragma unroll
        for (int km = 0; km < 4; ++km) {
            s16x8 pf[2], vf[4];
#pragma unroll
            for (int j = 0; j < 4; ++j)
                vf[j] = *(const s16x8*)&V[(size_t)(cq + j * 16 + lm) * HW +
                                          col0 + km * 32 + q * 8];
#pragma unroll
            for (int i = 0; i < 2; ++i)
                pf[i] = *(const s16x8*)&Ps[buf][(i * 16 + lm) * 136 + km * 32 + q * 8];
            __builtin_amdgcn_s_setprio(1);
#pragma unroll
            for (int i = 0; i < 2; ++i)
#pragma unroll
                for (int j = 0; j < 4; ++j)
                    oacc[i][j] = __builtin_amdgcn_mfma_f32_16x16x32_bf16(
                        pf[i], vf[j], oacc[i][j], 0, 0, 0);
            __builtin_amdgcn_s_setprio(0);
        }
    }

    // ---- rowsum reduce over lm lanes, then across waves
#pragma unroll
    for (int i = 0; i < 2; ++i)
#pragma unroll
        for (int r = 0; r < 4; ++r) {
            float s = rsum[i][r];
            s += __shfl_xor(s, 1, 64);
            s += __shfl_xor(s, 2, 64);
            s += __shfl_xor(s, 4, 64);
            s += __shfl_xor(s, 8, 64);
            if (lm == 0) rs[w * 32 + i * 16 + q * 4 + r] = s;
        }
    __syncthreads();

    // ---- normalize, store bf16 output, accumulate gate dot-product
    float gacc[2][4];
#pragma unroll
    for (int i = 0; i < 2; ++i)
#pragma unroll
        for (int r = 0; r < 4; ++r) {
            int row = i * 16 + q * 4 + r;
            float inv = 1.f / (rs[row] + rs[32 + row] + rs[64 + row] + rs[96 + row]);
            size_t base = (size_t)(r0 + row) * CCH;
            float ga = 0.f;
#pragma unroll
            for (int j = 0; j < 4; ++j) {
                short h = f2bf(oacc[i][j][r] * inv);
                Out[base + cq + j * 16 + lm] = h;
                ga = fmaf(bf2f(h), gwv[j], ga);
            }
            gacc[i][r] = ga;
        }
    // gate: reduce over lm, then across waves, sigmoid
#pragma unroll
    for (int i = 0; i < 2; ++i)
#pragma unroll
        for (int r = 0; r < 4; ++r) {
            float s = gacc[i][r];
            s += __shfl_xor(s, 1, 64);
            s += __shfl_xor(s, 2, 64);
            s += __shfl_xor(s, 4, 64);
            s += __shfl_xor(s, 8, 64);
            if (lm == 0) grs[w * 32 + i * 16 + q * 4 + r] = s;
        }
    __syncthreads();
    if (t < 32) {
        float g = grs[t] + grs[32 + t] + grs[64 + t] + grs[96 + t];
        mdst[r0 + t] = 1.f / (1.f + __expf(-g));
    }
}

// ---------------------------------------------------------------------------
// k_final (merged): half = blockIdx.z>>2 selects (W1,eattT,Xt16,m1,out1) vs
// (W2,qattT,Qt16,m2,out2). TM=128(o), TN=64(p), BK=32, two K=256 phases.
// grid (64, 2, 8), block 256.
// ---------------------------------------------------------------------------
__global__ __launch_bounds__(256) void k_final(const short* __restrict__ W16_1,
                                               const short* __restrict__ W16_2,
                                               const short* __restrict__ eattT,
                                               const short* __restrict__ qattT,
                                               const short* __restrict__ Xt16,
                                               const short* __restrict__ Qt16,
                                               const float* __restrict__ m1v,
                                               const float* __restrict__ m2v,
                                               float* __restrict__ outbase) {
    __shared__ short As[128 * 40];
    __shared__ short Bs[64 * 40];
    int t = threadIdx.x;
    int zz = blockIdx.z;
    int half = zz >> 2, b = zz & 3;
    const short* W16 = half ? W16_2 : W16_1;
    const short* attT = (half ? qattT : eattT);
    const short* inT  = (half ? Qt16 : Xt16);
    const float* gate = half ? m2v : m1v;
    float* outp = outbase + (size_t)half * BATCH * CCH * HW;
    int p0 = blockIdx.x * 64, o0 = blockIdx.y * 128;
    const short* Tb0 = attT + (size_t)b * HW * CCH;
    const short* Tb1 = inT + (size_t)b * HW * CCH;
    int lm = t & 15, q = (t >> 4) & 3, w = t >> 6;
    int wr = (w >> 1) * 64, wc = (w & 1) * 32;
    f32x4 acc[2][4][2];
#pragma unroll
    for (int ph = 0; ph < 2; ++ph)
#pragma unroll
        for (int i = 0; i < 4; ++i)
#pragma unroll
            for (int j = 0; j < 2; ++j) acc[ph][i][j] = (f32x4){0.f, 0.f, 0.f, 0.f};

    int brow = t >> 2, boff = (t & 3) * 8;
    for (int ph = 0; ph < 2; ++ph) {
        const short* Tb = ph ? Tb1 : Tb0;
        for (int k0 = 0; k0 < CCH; k0 += 32) {
#pragma unroll
            for (int u = 0; u < 2; ++u) {
                int chunk = t + u * 256;
                int row = chunk >> 2, off = (chunk & 3) * 8;
                *(float4*)&As[row * 40 + off] =
                    *(const float4*)&W16[(size_t)(o0 + row) * 512 + ph * 256 + k0 + off];
            }
            *(float4*)&Bs[brow * 40 + boff] =
                *(const float4*)&Tb[(size_t)(p0 + brow) * CCH + k0 + boff];
            __syncthreads();
            s16x8 af[4], bfr[2];
#pragma unroll
            for (int i = 0; i < 4; ++i)
                af[i] = *(const s16x8*)&As[(wr + i * 16 + lm) * 40 + q * 8];
#pragma unroll
            for (int j = 0; j < 2; ++j)
                bfr[j] = *(const s16x8*)&Bs[(wc + j * 16 + lm) * 40 + q * 8];
#pragma unroll
            for (int i = 0; i < 4; ++i)
#pragma unroll
                for (int j = 0; j < 2; ++j)
                    acc[ph][i][j] = __builtin_amdgcn_mfma_f32_16x16x32_bf16(
                        af[i], bfr[j], acc[ph][i][j], 0, 0, 0);
            __syncthreads();
        }
    }
#pragma unroll
    for (int j = 0; j < 2; ++j) {
        int p = p0 + wc + j * 16 + lm;
        float gv = gate[(size_t)b * HW + p];
#pragma unroll
        for (int i = 0; i < 4; ++i)
#pragma unroll
            for (int r = 0; r < 4; ++r) {
                int o = o0 + wr + i * 16 + q * 4 + r;
                outp[((size_t)b * CCH + o) * HW + p] =
                    acc[0][i][j][r] * gv + acc[1][i][j][r];
            }
    }
}

// ---------------------------------------------------------------------------
extern "C" void kernel_launch(void* const* d_in, const int* in_sizes, int n_in,
                              void* d_out, int out_size, void* d_ws, size_t ws_size,
                              hipStream_t stream) {
    (void)in_sizes; (void)n_in; (void)out_size; (void)ws_size;
    const float* in1 = (const float*)d_in[0];
    const float* in2 = (const float*)d_in[1];
    const float* We  = (const float*)d_in[2];
    const float* gw  = (const float*)d_in[3];
    const float* W1  = (const float*)d_in[4];
    const float* W2  = (const float*)d_in[5];
    float* out = (float*)d_out;
    char* ws = (char*)d_ws;

    const size_t SB = (size_t)BATCH * CCH * HW * 2;    // 8 MB bf16 tensor
    const size_t WB = (size_t)CCH * 2 * CCH * 2;       // 256 KB
    const size_t EB = (size_t)CCH * CCH * 2;           // 128 KB (We16)
    const size_t VB = (size_t)BATCH * NM * 4;          // 64 KB

    size_t off = 0;
    auto alloc = [&](size_t bytes) {
        char* p = ws + off;
        off += (bytes + 255) & ~(size_t)255;
        return p;
    };
    short* W16_1 = (short*)alloc(WB);
    short* W16_2 = (short*)alloc(WB);
    short* We16  = (short*)alloc(EB);
    short* Xt16  = (short*)alloc(SB);   // in1^T (b,p,c)
    short* Qt16  = (short*)alloc(SB);   // in2^T (b,p,c)
    short* E16n  = (short*)alloc(SB);   // (b,n,d)
    short* eattT = (short*)alloc(SB);
    short* qattT = (short*)alloc(SB);
    short* X16   = (short*)alloc(SB);   // in1 (b,c,p) bf16
    short* Q16   = (short*)alloc(SB);   // in2 (b,c,p) bf16
    float* m1v   = (float*)alloc(VB);
    float* m2v   = (float*)alloc(VB);

    const int nW = CCH * 2 * CCH;
    const int nWe = CCH * CCH;

    k_cast<<<dim3(nW / 1024), 256, 0, stream>>>(W1, W16_1, nW);
    k_cast<<<dim3(nW / 1024), 256, 0, stream>>>(W2, W16_2, nW);
    k_cast<<<dim3(nWe / 1024), 256, 0, stream>>>(We, We16, nWe);
    k_prep<<<dim3(HW / 64, CCH / 64, 8), 256, 0, stream>>>(in1, in2, X16, Q16,
                                                           Xt16, Qt16);

    k_E_mfma<<<dim3(2, 32, BATCH), 256, 0, stream>>>(Xt16, We16, E16n);

    k_fused<<<dim3((HW / 32) * 8), 256, 0, stream>>>(E16n, Qt16, Q16, X16, gw,
                                                     eattT, qattT, m1v, m2v);

    k_final<<<dim3(64, 2, 8), 256, 0, stream>>>(W16_1, W16_2, eattT, qattT,
                                                Xt16, Qt16, m1v, m2v, out);
}

// Round 3
// 375.014 us; speedup vs baseline: 1.6621x; 1.6621x over previous
//
#include <hip/hip_runtime.h>
#include <cstdint>
#include <cstddef>

#define BATCH 4
#define CCH   256
#define HW    4096
#define NM    4096

typedef __attribute__((ext_vector_type(8))) short s16x8;
typedef __attribute__((ext_vector_type(4))) float f32x4;

__device__ __forceinline__ short f2bf(float f) {
    unsigned u = __float_as_uint(f);
    u += 0x7FFFu + ((u >> 16) & 1u);
    return (short)(u >> 16);
}
__device__ __forceinline__ float bf2f(short s) {
    return __uint_as_float(((unsigned)(unsigned short)s) << 16);
}

// ---------------------------------------------------------------------------
// k_cast: fp32 -> bf16, same layout (weights only).
// ---------------------------------------------------------------------------
__global__ __launch_bounds__(256) void k_cast(const float* __restrict__ s,
                                              short* __restrict__ d, int n) {
    int i = (blockIdx.x * 256 + threadIdx.x) * 4;
    if (i + 3 < n) {
        float4 v = *(const float4*)&s[i];
        *(short4*)&d[i] = make_short4(f2bf(v.x), f2bf(v.y), f2bf(v.z), f2bf(v.w));
    }
}

// ---------------------------------------------------------------------------
// k_prep: one pass over in1/in2 producing direct bf16 (b,c,p) and transposed
// bf16 (b,p,c). grid (HW/64, CCH/64, 8): z = b*2+which.
// ---------------------------------------------------------------------------
__global__ __launch_bounds__(256) void k_prep(const float* __restrict__ in1,
                                              const float* __restrict__ in2,
                                              short* __restrict__ X16,
                                              short* __restrict__ Q16,
                                              short* __restrict__ Xt16,
                                              short* __restrict__ Qt16) {
    __shared__ short S[64][72];
    int t = threadIdx.x;
    int p0 = blockIdx.x * 64, c0 = blockIdx.y * 64;
    int z = blockIdx.z;
    int b = z >> 1, which = z & 1;
    const float* src = (which ? in2 : in1) + (size_t)b * CCH * HW;
    short* direct = (which ? Q16 : X16) + (size_t)b * CCH * HW;
    short* trans  = (which ? Qt16 : Xt16) + (size_t)b * HW * CCH;
    int tx = t & 15, ty = t >> 4;
#pragma unroll
    for (int i = 0; i < 4; ++i) {
        int c = ty + i * 16;
        float4 v = *(const float4*)&src[(size_t)(c0 + c) * HW + p0 + tx * 4];
        short4 h = make_short4(f2bf(v.x), f2bf(v.y), f2bf(v.z), f2bf(v.w));
        *(short4*)&direct[(size_t)(c0 + c) * HW + p0 + tx * 4] = h;
        S[tx * 4 + 0][c] = h.x;
        S[tx * 4 + 1][c] = h.y;
        S[tx * 4 + 2][c] = h.z;
        S[tx * 4 + 3][c] = h.w;
    }
    __syncthreads();
#pragma unroll
    for (int i = 0; i < 4; ++i) {
        int p = ty + i * 16;
        short4 v = *(const short4*)&S[p][tx * 4];
        *(short4*)&trans[(size_t)(p0 + p) * CCH + c0 + tx * 4] = v;
    }
}

// ---------------------------------------------------------------------------
// k_E_mfma: E16n[b,n,d] = bf16( sum_c Xt16[b,n,c] * We16[d,c] )
// TM=128(n), TN=128(d), BK=64, K=256. grid (2, 32, B), block 256.
// ---------------------------------------------------------------------------
__global__ __launch_bounds__(256) void k_E_mfma(const short* __restrict__ Xt16,
                                                const short* __restrict__ We16,
                                                short* __restrict__ E16n) {
    __shared__ short As[128 * 72];
    __shared__ short Bs[128 * 72];
    int t = threadIdx.x;
    int d0 = blockIdx.x * 128, n0 = blockIdx.y * 128, b = blockIdx.z;
    const short* Xb = Xt16 + (size_t)b * HW * CCH;
    short* Eb = E16n + (size_t)b * HW * CCH;
    int lm = t & 15, q = (t >> 4) & 3, w = t >> 6;
    int wr = (w >> 1) * 64, wc = (w & 1) * 64;
    f32x4 acc[4][4];
#pragma unroll
    for (int i = 0; i < 4; ++i)
#pragma unroll
        for (int j = 0; j < 4; ++j) acc[i][j] = (f32x4){0.f, 0.f, 0.f, 0.f};

    for (int k0 = 0; k0 < CCH; k0 += 64) {
#pragma unroll
        for (int u = 0; u < 4; ++u) {
            int chunk = t + u * 256;
            int row = chunk >> 3, off = (chunk & 7) * 8;
            *(float4*)&As[row * 72 + off] =
                *(const float4*)&Xb[(size_t)(n0 + row) * CCH + k0 + off];
            *(float4*)&Bs[row * 72 + off] =
                *(const float4*)&We16[(size_t)(d0 + row) * CCH + k0 + off];
        }
        __syncthreads();
#pragma unroll
        for (int kk = 0; kk < 2; ++kk) {
            s16x8 af[4], bfr[4];
#pragma unroll
            for (int i = 0; i < 4; ++i)
                af[i] = *(const s16x8*)&As[(wr + i * 16 + lm) * 72 + kk * 32 + q * 8];
#pragma unroll
            for (int j = 0; j < 4; ++j)
                bfr[j] = *(const s16x8*)&Bs[(wc + j * 16 + lm) * 72 + kk * 32 + q * 8];
#pragma unroll
            for (int i = 0; i < 4; ++i)
#pragma unroll
                for (int j = 0; j < 4; ++j)
                    acc[i][j] = __builtin_amdgcn_mfma_f32_16x16x32_bf16(
                        af[i], bfr[j], acc[i][j], 0, 0, 0);
        }
        __syncthreads();
    }
#pragma unroll
    for (int i = 0; i < 4; ++i)
#pragma unroll
        for (int r = 0; r < 4; ++r) {
            size_t base = (size_t)(n0 + wr + i * 16 + q * 4 + r) * CCH;
#pragma unroll
            for (int j = 0; j < 4; ++j)
                Eb[base + d0 + wc + j * 16 + lm] = f2bf(acc[i][j][r]);
        }
}

// ---------------------------------------------------------------------------
// k_fused v5: 128 rows/block (grid 256 = 1 block/CU). Rationale: k_fused is
// L2/L3-fabric-BW bound (~7.5 TB/s observed across v3/v4); traffic per unit
// = row_blocks x 4MB (Ac+V full stream). 128-row blocks HALVE traffic vs v3.
// At 1 block/CU, full LDS (141 KB: ArS 67.6 + Ps dbuf 69.6) and 512 VGPR/wave
// budgets are available. Dataflow identical to v3: col-split score (wave w =
// 32 score cols), LDS Ps round-trip, channel-split PV (wave w = 64 channels).
// Single barrier per col-tile via Ps double-buffer (v4-verified logic).
// unit = gid&7 == XCD: 32 blocks on the unit's 32 CUs, Ac/V L2-resident.
// ---------------------------------------------------------------------------
__global__ __launch_bounds__(256, 1) void k_fused(const short* __restrict__ E16n,
                                                  const short* __restrict__ Qt16,
                                                  const short* __restrict__ Q16,
                                                  const short* __restrict__ X16,
                                                  const float* __restrict__ gw,
                                                  short* __restrict__ eattT,
                                                  short* __restrict__ qattT,
                                                  float* __restrict__ m1v,
                                                  float* __restrict__ m2v) {
    __shared__ short ArS[128 * 264];    // 67.6 KB (132 dw stride; mod-32 = 4)
    __shared__ short Ps[2][128 * 136];  // 69.6 KB double-buffered (68 dw stride)
    __shared__ float rs[4 * 128];       // 2 KB rowsum cross-wave
    __shared__ float grs[4 * 128];      // 2 KB gate-dot cross-wave

    int t = threadIdx.x;
    int gid = blockIdx.x;
    int unit = gid & 7;
    int b = unit >> 1, which = unit & 1;
    int r0 = (gid >> 3) * 128;

    const short* Ar = (which ? Qt16 : E16n) + (size_t)b * HW * CCH;
    const short* Ac = (which ? E16n : Qt16) + (size_t)b * HW * CCH;
    const short* V  = (which ? X16  : Q16 ) + (size_t)b * CCH * HW;
    short* Out = (which ? qattT : eattT) + (size_t)b * HW * CCH;
    float* mdst = (which ? m2v : m1v) + (size_t)b * HW;

    int lm = t & 15, q = (t >> 4) & 3, w = t >> 6;
    int wqs = w * 32;   // this wave's score-column quarter (of 128)
    int cq  = w * 64;   // this wave's V-channel quarter (of 256)

    // gate weights for this lane's 4 channels
    float gwv[4];
#pragma unroll
    for (int j = 0; j < 4; ++j) gwv[j] = gw[cq + j * 16 + lm];

    // ---- preload Ar rows [r0, r0+128) x K=256 into LDS (once; 64 KB)
#pragma unroll
    for (int u = 0; u < 16; ++u) {
        int chunk = t + u * 256;
        int row = chunk >> 5, off = (chunk & 31) * 8;
        *(float4*)&ArS[row * 264 + off] =
            *(const float4*)&Ar[(size_t)(r0 + row) * CCH + off];
    }
    __syncthreads();

    f32x4 oacc[8][4];
    float rsum[8][4];
#pragma unroll
    for (int i = 0; i < 8; ++i) {
#pragma unroll
        for (int j = 0; j < 4; ++j) oacc[i][j] = (f32x4){0.f, 0.f, 0.f, 0.f};
#pragma unroll
        for (int r = 0; r < 4; ++r) rsum[i][r] = 0.f;
    }

    int buf = 0;
    for (int col0 = 0; col0 < NM; col0 += 128, buf ^= 1) {
        // ---- score: S[128][128] = Ar . Ac[col0:+128]^T  (barrier-free)
        f32x4 sacc[8][2];
#pragma unroll
        for (int i = 0; i < 8; ++i)
#pragma unroll
            for (int j = 0; j < 2; ++j) sacc[i][j] = (f32x4){0.f, 0.f, 0.f, 0.f};
#pragma unroll
        for (int kk = 0; kk < 8; ++kk) {
            s16x8 af[8], bf[2];
#pragma unroll
            for (int i = 0; i < 8; ++i)
                af[i] = *(const s16x8*)&ArS[(i * 16 + lm) * 264 + kk * 32 + q * 8];
#pragma unroll
            for (int j = 0; j < 2; ++j)
                bf[j] = *(const s16x8*)&Ac[(size_t)(col0 + wqs + j * 16 + lm) * CCH +
                                           kk * 32 + q * 8];
#pragma unroll
            for (int i = 0; i < 8; ++i)
#pragma unroll
                for (int j = 0; j < 2; ++j)
                    sacc[i][j] = __builtin_amdgcn_mfma_f32_16x16x32_bf16(
                        af[i], bf[j], sacc[i][j], 0, 0, 0);
        }
        // ---- exp in registers (bf16-rounded value kept in sacc)
#pragma unroll
        for (int i = 0; i < 8; ++i)
#pragma unroll
            for (int j = 0; j < 2; ++j)
#pragma unroll
                for (int r = 0; r < 4; ++r) {
                    float v = bf2f(f2bf(__expf(sacc[i][j][r])));
                    rsum[i][r] += v;
                    sacc[i][j][r] = v;
                }
        // write this tile's P into buffer `buf`; safe without a pre-barrier:
        // all waves' PV reads of Ps[buf] (tile t-2) completed before the
        // barrier of tile t-1, which every wave has passed.
#pragma unroll
        for (int i = 0; i < 8; ++i)
#pragma unroll
            for (int j = 0; j < 2; ++j)
#pragma unroll
                for (int r = 0; r < 4; ++r)
                    Ps[buf][(i * 16 + q * 4 + r) * 136 + wqs + j * 16 + lm] =
                        (short)(__float_as_uint(sacc[i][j][r]) >> 16);
        __syncthreads();   // Ps[buf] visible to all waves
        // ---- PV: oacc += P[:, tile] . V[:, tile]^T
#pragma unroll
        for (int km = 0; km < 4; ++km) {
            s16x8 pf[8], vf[4];
#pragma unroll
            for (int j = 0; j < 4; ++j)
                vf[j] = *(const s16x8*)&V[(size_t)(cq + j * 16 + lm) * HW +
                                          col0 + km * 32 + q * 8];
#pragma unroll
            for (int i = 0; i < 8; ++i)
                pf[i] = *(const s16x8*)&Ps[buf][(i * 16 + lm) * 136 + km * 32 + q * 8];
#pragma unroll
            for (int i = 0; i < 8; ++i)
#pragma unroll
                for (int j = 0; j < 4; ++j)
                    oacc[i][j] = __builtin_amdgcn_mfma_f32_16x16x32_bf16(
                        pf[i], vf[j], oacc[i][j], 0, 0, 0);
        }
    }

    // ---- rowsum reduce over lm lanes, then across waves
#pragma unroll
    for (int i = 0; i < 8; ++i)
#pragma unroll
        for (int r = 0; r < 4; ++r) {
            float s = rsum[i][r];
            s += __shfl_xor(s, 1, 64);
            s += __shfl_xor(s, 2, 64);
            s += __shfl_xor(s, 4, 64);
            s += __shfl_xor(s, 8, 64);
            if (lm == 0) rs[w * 128 + i * 16 + q * 4 + r] = s;
        }
    __syncthreads();

    // ---- normalize, store bf16 output, accumulate gate dot-product
    float gacc[8][4];
#pragma unroll
    for (int i = 0; i < 8; ++i)
#pragma unroll
        for (int r = 0; r < 4; ++r) {
            int row = i * 16 + q * 4 + r;
            float inv = 1.f / (rs[row] + rs[128 + row] + rs[256 + row] + rs[384 + row]);
            size_t base = (size_t)(r0 + row) * CCH;
            float ga = 0.f;
#pragma unroll
            for (int j = 0; j < 4; ++j) {
                short h = f2bf(oacc[i][j][r] * inv);
                Out[base + cq + j * 16 + lm] = h;
                ga = fmaf(bf2f(h), gwv[j], ga);
            }
            gacc[i][r] = ga;
        }
    // gate: reduce over lm, then across waves, sigmoid
#pragma unroll
    for (int i = 0; i < 8; ++i)
#pragma unroll
        for (int r = 0; r < 4; ++r) {
            float s = gacc[i][r];
            s += __shfl_xor(s, 1, 64);
            s += __shfl_xor(s, 2, 64);
            s += __shfl_xor(s, 4, 64);
            s += __shfl_xor(s, 8, 64);
            if (lm == 0) grs[w * 128 + i * 16 + q * 4 + r] = s;
        }
    __syncthreads();
    if (t < 128) {
        float g = grs[t] + grs[128 + t] + grs[256 + t] + grs[384 + t];
        mdst[r0 + t] = 1.f / (1.f + __expf(-g));
    }
}

// ---------------------------------------------------------------------------
// k_final (merged): half = blockIdx.z>>2 selects (W1,eattT,Xt16,m1,out1) vs
// (W2,qattT,Qt16,m2,out2). TM=128(o), TN=64(p), BK=32, two K=256 phases.
// grid (64, 2, 8), block 256.
// ---------------------------------------------------------------------------
__global__ __launch_bounds__(256) void k_final(const short* __restrict__ W16_1,
                                               const short* __restrict__ W16_2,
                                               const short* __restrict__ eattT,
                                               const short* __restrict__ qattT,
                                               const short* __restrict__ Xt16,
                                               const short* __restrict__ Qt16,
                                               const float* __restrict__ m1v,
                                               const float* __restrict__ m2v,
                                               float* __restrict__ outbase) {
    __shared__ short As[128 * 40];
    __shared__ short Bs[64 * 40];
    int t = threadIdx.x;
    int zz = blockIdx.z;
    int half = zz >> 2, b = zz & 3;
    const short* W16 = half ? W16_2 : W16_1;
    const short* attT = (half ? qattT : eattT);
    const short* inT  = (half ? Qt16 : Xt16);
    const float* gate = half ? m2v : m1v;
    float* outp = outbase + (size_t)half * BATCH * CCH * HW;
    int p0 = blockIdx.x * 64, o0 = blockIdx.y * 128;
    const short* Tb0 = attT + (size_t)b * HW * CCH;
    const short* Tb1 = inT + (size_t)b * HW * CCH;
    int lm = t & 15, q = (t >> 4) & 3, w = t >> 6;
    int wr = (w >> 1) * 64, wc = (w & 1) * 32;
    f32x4 acc[2][4][2];
#pragma unroll
    for (int ph = 0; ph < 2; ++ph)
#pragma unroll
        for (int i = 0; i < 4; ++i)
#pragma unroll
            for (int j = 0; j < 2; ++j) acc[ph][i][j] = (f32x4){0.f, 0.f, 0.f, 0.f};

    int brow = t >> 2, boff = (t & 3) * 8;
    for (int ph = 0; ph < 2; ++ph) {
        const short* Tb = ph ? Tb1 : Tb0;
        for (int k0 = 0; k0 < CCH; k0 += 32) {
#pragma unroll
            for (int u = 0; u < 2; ++u) {
                int chunk = t + u * 256;
                int row = chunk >> 2, off = (chunk & 3) * 8;
                *(float4*)&As[row * 40 + off] =
                    *(const float4*)&W16[(size_t)(o0 + row) * 512 + ph * 256 + k0 + off];
            }
            *(float4*)&Bs[brow * 40 + boff] =
                *(const float4*)&Tb[(size_t)(p0 + brow) * CCH + k0 + boff];
            __syncthreads();
            s16x8 af[4], bfr[2];
#pragma unroll
            for (int i = 0; i < 4; ++i)
                af[i] = *(const s16x8*)&As[(wr + i * 16 + lm) * 40 + q * 8];
#pragma unroll
            for (int j = 0; j < 2; ++j)
                bfr[j] = *(const s16x8*)&Bs[(wc + j * 16 + lm) * 40 + q * 8];
#pragma unroll
            for (int i = 0; i < 4; ++i)
#pragma unroll
                for (int j = 0; j < 2; ++j)
                    acc[ph][i][j] = __builtin_amdgcn_mfma_f32_16x16x32_bf16(
                        af[i], bfr[j], acc[ph][i][j], 0, 0, 0);
            __syncthreads();
        }
    }
#pragma unroll
    for (int j = 0; j < 2; ++j) {
        int p = p0 + wc + j * 16 + lm;
        float gv = gate[(size_t)b * HW + p];
#pragma unroll
        for (int i = 0; i < 4; ++i)
#pragma unroll
            for (int r = 0; r < 4; ++r) {
                int o = o0 + wr + i * 16 + q * 4 + r;
                outp[((size_t)b * CCH + o) * HW + p] =
                    acc[0][i][j][r] * gv + acc[1][i][j][r];
            }
    }
}

// ---------------------------------------------------------------------------
extern "C" void kernel_launch(void* const* d_in, const int* in_sizes, int n_in,
                              void* d_out, int out_size, void* d_ws, size_t ws_size,
                              hipStream_t stream) {
    (void)in_sizes; (void)n_in; (void)out_size; (void)ws_size;
    const float* in1 = (const float*)d_in[0];
    const float* in2 = (const float*)d_in[1];
    const float* We  = (const float*)d_in[2];
    const float* gw  = (const float*)d_in[3];
    const float* W1  = (const float*)d_in[4];
    const float* W2  = (const float*)d_in[5];
    float* out = (float*)d_out;
    char* ws = (char*)d_ws;

    const size_t SB = (size_t)BATCH * CCH * HW * 2;    // 8 MB bf16 tensor
    const size_t WB = (size_t)CCH * 2 * CCH * 2;       // 256 KB
    const size_t EB = (size_t)CCH * CCH * 2;           // 128 KB (We16)
    const size_t VB = (size_t)BATCH * NM * 4;          // 64 KB

    size_t off = 0;
    auto alloc = [&](size_t bytes) {
        char* p = ws + off;
        off += (bytes + 255) & ~(size_t)255;
        return p;
    };
    short* W16_1 = (short*)alloc(WB);
    short* W16_2 = (short*)alloc(WB);
    short* We16  = (short*)alloc(EB);
    short* Xt16  = (short*)alloc(SB);   // in1^T (b,p,c)
    short* Qt16  = (short*)alloc(SB);   // in2^T (b,p,c)
    short* E16n  = (short*)alloc(SB);   // (b,n,d)
    short* eattT = (short*)alloc(SB);
    short* qattT = (short*)alloc(SB);
    short* X16   = (short*)alloc(SB);   // in1 (b,c,p) bf16
    short* Q16   = (short*)alloc(SB);   // in2 (b,c,p) bf16
    float* m1v   = (float*)alloc(VB);
    float* m2v   = (float*)alloc(VB);

    const int nW = CCH * 2 * CCH;
    const int nWe = CCH * CCH;

    k_cast<<<dim3(nW / 1024), 256, 0, stream>>>(W1, W16_1, nW);
    k_cast<<<dim3(nW / 1024), 256, 0, stream>>>(W2, W16_2, nW);
    k_cast<<<dim3(nWe / 1024), 256, 0, stream>>>(We, We16, nWe);
    k_prep<<<dim3(HW / 64, CCH / 64, 8), 256, 0, stream>>>(in1, in2, X16, Q16,
                                                           Xt16, Qt16);

    k_E_mfma<<<dim3(2, 32, BATCH), 256, 0, stream>>>(Xt16, We16, E16n);

    k_fused<<<dim3((HW / 128) * 8), 256, 0, stream>>>(E16n, Qt16, Q16, X16, gw,
                                                      eattT, qattT, m1v, m2v);

    k_final<<<dim3(64, 2, 8), 256, 0, stream>>>(W16_1, W16_2, eattT, qattT,
                                                Xt16, Qt16, m1v, m2v, out);
}

// Round 4
// 303.917 us; speedup vs baseline: 2.0509x; 1.2339x over previous
//
#include <hip/hip_runtime.h>
#include <cstdint>
#include <cstddef>

#define BATCH 4
#define CCH   256
#define HW    4096
#define NM    4096

typedef __attribute__((ext_vector_type(8))) short s16x8;
typedef __attribute__((ext_vector_type(4))) float f32x4;

__device__ __forceinline__ short f2bf(float f) {
    unsigned u = __float_as_uint(f);
    u += 0x7FFFu + ((u >> 16) & 1u);
    return (short)(u >> 16);
}
__device__ __forceinline__ float bf2f(short s) {
    return __uint_as_float(((unsigned)(unsigned short)s) << 16);
}

// ---------------------------------------------------------------------------
// k_cast: fp32 -> bf16, same layout (weights only).
// ---------------------------------------------------------------------------
__global__ __launch_bounds__(256) void k_cast(const float* __restrict__ s,
                                              short* __restrict__ d, int n) {
    int i = (blockIdx.x * 256 + threadIdx.x) * 4;
    if (i + 3 < n) {
        float4 v = *(const float4*)&s[i];
        *(short4*)&d[i] = make_short4(f2bf(v.x), f2bf(v.y), f2bf(v.z), f2bf(v.w));
    }
}

// ---------------------------------------------------------------------------
// k_prep: one pass over in1/in2 producing direct bf16 (b,c,p) and transposed
// bf16 (b,p,c). grid (HW/64, CCH/64, 8): z = b*2+which.
// ---------------------------------------------------------------------------
__global__ __launch_bounds__(256) void k_prep(const float* __restrict__ in1,
                                              const float* __restrict__ in2,
                                              short* __restrict__ X16,
                                              short* __restrict__ Q16,
                                              short* __restrict__ Xt16,
                                              short* __restrict__ Qt16) {
    __shared__ short S[64][72];
    int t = threadIdx.x;
    int p0 = blockIdx.x * 64, c0 = blockIdx.y * 64;
    int z = blockIdx.z;
    int b = z >> 1, which = z & 1;
    const float* src = (which ? in2 : in1) + (size_t)b * CCH * HW;
    short* direct = (which ? Q16 : X16) + (size_t)b * CCH * HW;
    short* trans  = (which ? Qt16 : Xt16) + (size_t)b * HW * CCH;
    int tx = t & 15, ty = t >> 4;
#pragma unroll
    for (int i = 0; i < 4; ++i) {
        int c = ty + i * 16;
        float4 v = *(const float4*)&src[(size_t)(c0 + c) * HW + p0 + tx * 4];
        short4 h = make_short4(f2bf(v.x), f2bf(v.y), f2bf(v.z), f2bf(v.w));
        *(short4*)&direct[(size_t)(c0 + c) * HW + p0 + tx * 4] = h;
        S[tx * 4 + 0][c] = h.x;
        S[tx * 4 + 1][c] = h.y;
        S[tx * 4 + 2][c] = h.z;
        S[tx * 4 + 3][c] = h.w;
    }
    __syncthreads();
#pragma unroll
    for (int i = 0; i < 4; ++i) {
        int p = ty + i * 16;
        short4 v = *(const short4*)&S[p][tx * 4];
        *(short4*)&trans[(size_t)(p0 + p) * CCH + c0 + tx * 4] = v;
    }
}

// ---------------------------------------------------------------------------
// k_E_mfma: E16n[b,n,d] = bf16( sum_c Xt16[b,n,c] * We16[d,c] )
// TM=128(n), TN=128(d), BK=64, K=256. grid (2, 32, B), block 256.
// ---------------------------------------------------------------------------
__global__ __launch_bounds__(256) void k_E_mfma(const short* __restrict__ Xt16,
                                                const short* __restrict__ We16,
                                                short* __restrict__ E16n) {
    __shared__ short As[128 * 72];
    __shared__ short Bs[128 * 72];
    int t = threadIdx.x;
    int d0 = blockIdx.x * 128, n0 = blockIdx.y * 128, b = blockIdx.z;
    const short* Xb = Xt16 + (size_t)b * HW * CCH;
    short* Eb = E16n + (size_t)b * HW * CCH;
    int lm = t & 15, q = (t >> 4) & 3, w = t >> 6;
    int wr = (w >> 1) * 64, wc = (w & 1) * 64;
    f32x4 acc[4][4];
#pragma unroll
    for (int i = 0; i < 4; ++i)
#pragma unroll
        for (int j = 0; j < 4; ++j) acc[i][j] = (f32x4){0.f, 0.f, 0.f, 0.f};

    for (int k0 = 0; k0 < CCH; k0 += 64) {
#pragma unroll
        for (int u = 0; u < 4; ++u) {
            int chunk = t + u * 256;
            int row = chunk >> 3, off = (chunk & 7) * 8;
            *(float4*)&As[row * 72 + off] =
                *(const float4*)&Xb[(size_t)(n0 + row) * CCH + k0 + off];
            *(float4*)&Bs[row * 72 + off] =
                *(const float4*)&We16[(size_t)(d0 + row) * CCH + k0 + off];
        }
        __syncthreads();
#pragma unroll
        for (int kk = 0; kk < 2; ++kk) {
            s16x8 af[4], bfr[4];
#pragma unroll
            for (int i = 0; i < 4; ++i)
                af[i] = *(const s16x8*)&As[(wr + i * 16 + lm) * 72 + kk * 32 + q * 8];
#pragma unroll
            for (int j = 0; j < 4; ++j)
                bfr[j] = *(const s16x8*)&Bs[(wc + j * 16 + lm) * 72 + kk * 32 + q * 8];
#pragma unroll
            for (int i = 0; i < 4; ++i)
#pragma unroll
                for (int j = 0; j < 4; ++j)
                    acc[i][j] = __builtin_amdgcn_mfma_f32_16x16x32_bf16(
                        af[i], bfr[j], acc[i][j], 0, 0, 0);
        }
        __syncthreads();
    }
#pragma unroll
    for (int i = 0; i < 4; ++i)
#pragma unroll
        for (int r = 0; r < 4; ++r) {
            size_t base = (size_t)(n0 + wr + i * 16 + q * 4 + r) * CCH;
#pragma unroll
            for (int j = 0; j < 4; ++j)
                Eb[base + d0 + wc + j * 16 + lm] = f2bf(acc[i][j][r]);
        }
}

// ---------------------------------------------------------------------------
// k_fused v6: 128 rows/block (grid 256 = 1 block/CU) with 512 threads =
// 8 waves = 2 waves/SIMD. v5 post-mortem: traffic halving worked but per-CU
// read throughput fell to 15.7 GB/s (1 wave/SIMD exposes L2/L3 latency);
// v3/v4 plateaued at ~30 GB/s/CU with 2 waves/SIMD. v6 keeps v5's traffic
// shape and restores the latency-hiding wave count. Work split: score cols
// 16/wave, PV channels 32/wave. Dataflow/layouts identical to v5.
// LDS 145 KB (ArS 67.6 + Ps dbuf 69.6 + rs/grs 8), 1 block/CU.
// unit = gid&7 == XCD: 32 blocks on the unit's 32 CUs, Ac/V L2-resident.
// ---------------------------------------------------------------------------
__global__ __launch_bounds__(512, 2) void k_fused(const short* __restrict__ E16n,
                                                  const short* __restrict__ Qt16,
                                                  const short* __restrict__ Q16,
                                                  const short* __restrict__ X16,
                                                  const float* __restrict__ gw,
                                                  short* __restrict__ eattT,
                                                  short* __restrict__ qattT,
                                                  float* __restrict__ m1v,
                                                  float* __restrict__ m2v) {
    __shared__ short ArS[128 * 264];    // 67.6 KB (132 dw stride; mod-32 = 4)
    __shared__ short Ps[2][128 * 136];  // 69.6 KB double-buffered (68 dw stride)
    __shared__ float rs[8 * 128];       // 4 KB rowsum cross-wave
    __shared__ float grs[8 * 128];      // 4 KB gate-dot cross-wave

    int t = threadIdx.x;
    int gid = blockIdx.x;
    int unit = gid & 7;
    int b = unit >> 1, which = unit & 1;
    int r0 = (gid >> 3) * 128;

    const short* Ar = (which ? Qt16 : E16n) + (size_t)b * HW * CCH;
    const short* Ac = (which ? E16n : Qt16) + (size_t)b * HW * CCH;
    const short* V  = (which ? X16  : Q16 ) + (size_t)b * CCH * HW;
    short* Out = (which ? qattT : eattT) + (size_t)b * HW * CCH;
    float* mdst = (which ? m2v : m1v) + (size_t)b * HW;

    int lm = t & 15, q = (t >> 4) & 3, w = t >> 6;   // w in [0,8)
    int wqs = w * 16;   // this wave's score-column slice (16 of 128)
    int cq  = w * 32;   // this wave's V-channel slice (32 of 256)

    // gate weights for this lane's 2 channels
    float gwv[2];
#pragma unroll
    for (int j = 0; j < 2; ++j) gwv[j] = gw[cq + j * 16 + lm];

    // ---- preload Ar rows [r0, r0+128) x K=256 into LDS (once; 64 KB)
#pragma unroll
    for (int u = 0; u < 8; ++u) {
        int chunk = t + u * 512;
        int row = chunk >> 5, off = (chunk & 31) * 8;
        *(float4*)&ArS[row * 264 + off] =
            *(const float4*)&Ar[(size_t)(r0 + row) * CCH + off];
    }
    __syncthreads();

    f32x4 oacc[8][2];
    float rsum[8][4];
#pragma unroll
    for (int i = 0; i < 8; ++i) {
#pragma unroll
        for (int j = 0; j < 2; ++j) oacc[i][j] = (f32x4){0.f, 0.f, 0.f, 0.f};
#pragma unroll
        for (int r = 0; r < 4; ++r) rsum[i][r] = 0.f;
    }

    int buf = 0;
    for (int col0 = 0; col0 < NM; col0 += 128, buf ^= 1) {
        // ---- score: S[128][wqs:wqs+16] = Ar . Ac[col0+wqs:+16]^T (barrier-free)
        f32x4 sacc[8];
#pragma unroll
        for (int i = 0; i < 8; ++i) sacc[i] = (f32x4){0.f, 0.f, 0.f, 0.f};
#pragma unroll
        for (int kk = 0; kk < 8; ++kk) {
            s16x8 af[8], bf;
#pragma unroll
            for (int i = 0; i < 8; ++i)
                af[i] = *(const s16x8*)&ArS[(i * 16 + lm) * 264 + kk * 32 + q * 8];
            bf = *(const s16x8*)&Ac[(size_t)(col0 + wqs + lm) * CCH + kk * 32 + q * 8];
#pragma unroll
            for (int i = 0; i < 8; ++i)
                sacc[i] = __builtin_amdgcn_mfma_f32_16x16x32_bf16(
                    af[i], bf, sacc[i], 0, 0, 0);
        }
        // ---- exp in registers (bf16-rounded value kept in sacc)
#pragma unroll
        for (int i = 0; i < 8; ++i)
#pragma unroll
            for (int r = 0; r < 4; ++r) {
                float v = bf2f(f2bf(__expf(sacc[i][r])));
                rsum[i][r] += v;
                sacc[i][r] = v;
            }
        // write this tile's P into buffer `buf`; safe without a pre-barrier:
        // all waves' PV reads of Ps[buf] (tile t-2) completed before the
        // barrier of tile t-1, which every wave has passed.
#pragma unroll
        for (int i = 0; i < 8; ++i)
#pragma unroll
            for (int r = 0; r < 4; ++r)
                Ps[buf][(i * 16 + q * 4 + r) * 136 + wqs + lm] =
                    (short)(__float_as_uint(sacc[i][r]) >> 16);
        __syncthreads();   // Ps[buf] visible to all waves
        // ---- PV: oacc += P[:, tile] . V[:, tile]^T
#pragma unroll
        for (int km = 0; km < 4; ++km) {
            s16x8 pf[8], vf[2];
#pragma unroll
            for (int j = 0; j < 2; ++j)
                vf[j] = *(const s16x8*)&V[(size_t)(cq + j * 16 + lm) * HW +
                                          col0 + km * 32 + q * 8];
#pragma unroll
            for (int i = 0; i < 8; ++i)
                pf[i] = *(const s16x8*)&Ps[buf][(i * 16 + lm) * 136 + km * 32 + q * 8];
#pragma unroll
            for (int i = 0; i < 8; ++i)
#pragma unroll
                for (int j = 0; j < 2; ++j)
                    oacc[i][j] = __builtin_amdgcn_mfma_f32_16x16x32_bf16(
                        pf[i], vf[j], oacc[i][j], 0, 0, 0);
        }
    }

    // ---- rowsum reduce over lm lanes, then across waves
#pragma unroll
    for (int i = 0; i < 8; ++i)
#pragma unroll
        for (int r = 0; r < 4; ++r) {
            float s = rsum[i][r];
            s += __shfl_xor(s, 1, 64);
            s += __shfl_xor(s, 2, 64);
            s += __shfl_xor(s, 4, 64);
            s += __shfl_xor(s, 8, 64);
            if (lm == 0) rs[w * 128 + i * 16 + q * 4 + r] = s;
        }
    __syncthreads();

    // ---- normalize, store bf16 output, accumulate gate dot-product
    float gacc[8][4];
#pragma unroll
    for (int i = 0; i < 8; ++i)
#pragma unroll
        for (int r = 0; r < 4; ++r) {
            int row = i * 16 + q * 4 + r;
            float tot = 0.f;
#pragma unroll
            for (int ww = 0; ww < 8; ++ww) tot += rs[ww * 128 + row];
            float inv = 1.f / tot;
            size_t base = (size_t)(r0 + row) * CCH;
            float ga = 0.f;
#pragma unroll
            for (int j = 0; j < 2; ++j) {
                short h = f2bf(oacc[i][j][r] * inv);
                Out[base + cq + j * 16 + lm] = h;
                ga = fmaf(bf2f(h), gwv[j], ga);
            }
            gacc[i][r] = ga;
        }
    // gate: reduce over lm, then across waves, sigmoid
#pragma unroll
    for (int i = 0; i < 8; ++i)
#pragma unroll
        for (int r = 0; r < 4; ++r) {
            float s = gacc[i][r];
            s += __shfl_xor(s, 1, 64);
            s += __shfl_xor(s, 2, 64);
            s += __shfl_xor(s, 4, 64);
            s += __shfl_xor(s, 8, 64);
            if (lm == 0) grs[w * 128 + i * 16 + q * 4 + r] = s;
        }
    __syncthreads();
    if (t < 128) {
        float g = 0.f;
#pragma unroll
        for (int ww = 0; ww < 8; ++ww) g += grs[ww * 128 + t];
        mdst[r0 + t] = 1.f / (1.f + __expf(-g));
    }
}

// ---------------------------------------------------------------------------
// k_final (merged): half = blockIdx.z>>2 selects (W1,eattT,Xt16,m1,out1) vs
// (W2,qattT,Qt16,m2,out2). TM=128(o), TN=64(p), BK=32, two K=256 phases.
// grid (64, 2, 8), block 256.
// ---------------------------------------------------------------------------
__global__ __launch_bounds__(256) void k_final(const short* __restrict__ W16_1,
                                               const short* __restrict__ W16_2,
                                               const short* __restrict__ eattT,
                                               const short* __restrict__ qattT,
                                               const short* __restrict__ Xt16,
                                               const short* __restrict__ Qt16,
                                               const float* __restrict__ m1v,
                                               const float* __restrict__ m2v,
                                               float* __restrict__ outbase) {
    __shared__ short As[128 * 40];
    __shared__ short Bs[64 * 40];
    int t = threadIdx.x;
    int zz = blockIdx.z;
    int half = zz >> 2, b = zz & 3;
    const short* W16 = half ? W16_2 : W16_1;
    const short* attT = (half ? qattT : eattT);
    const short* inT  = (half ? Qt16 : Xt16);
    const float* gate = half ? m2v : m1v;
    float* outp = outbase + (size_t)half * BATCH * CCH * HW;
    int p0 = blockIdx.x * 64, o0 = blockIdx.y * 128;
    const short* Tb0 = attT + (size_t)b * HW * CCH;
    const short* Tb1 = inT + (size_t)b * HW * CCH;
    int lm = t & 15, q = (t >> 4) & 3, w = t >> 6;
    int wr = (w >> 1) * 64, wc = (w & 1) * 32;
    f32x4 acc[2][4][2];
#pragma unroll
    for (int ph = 0; ph < 2; ++ph)
#pragma unroll
        for (int i = 0; i < 4; ++i)
#pragma unroll
            for (int j = 0; j < 2; ++j) acc[ph][i][j] = (f32x4){0.f, 0.f, 0.f, 0.f};

    int brow = t >> 2, boff = (t & 3) * 8;
    for (int ph = 0; ph < 2; ++ph) {
        const short* Tb = ph ? Tb1 : Tb0;
        for (int k0 = 0; k0 < CCH; k0 += 32) {
#pragma unroll
            for (int u = 0; u < 2; ++u) {
                int chunk = t + u * 256;
                int row = chunk >> 2, off = (chunk & 3) * 8;
                *(float4*)&As[row * 40 + off] =
                    *(const float4*)&W16[(size_t)(o0 + row) * 512 + ph * 256 + k0 + off];
            }
            *(float4*)&Bs[brow * 40 + boff] =
                *(const float4*)&Tb[(size_t)(p0 + brow) * CCH + k0 + boff];
            __syncthreads();
            s16x8 af[4], bfr[2];
#pragma unroll
            for (int i = 0; i < 4; ++i)
                af[i] = *(const s16x8*)&As[(wr + i * 16 + lm) * 40 + q * 8];
#pragma unroll
            for (int j = 0; j < 2; ++j)
                bfr[j] = *(const s16x8*)&Bs[(wc + j * 16 + lm) * 40 + q * 8];
#pragma unroll
            for (int i = 0; i < 4; ++i)
#pragma unroll
                for (int j = 0; j < 2; ++j)
                    acc[ph][i][j] = __builtin_amdgcn_mfma_f32_16x16x32_bf16(
                        af[i], bfr[j], acc[ph][i][j], 0, 0, 0);
            __syncthreads();
        }
    }
#pragma unroll
    for (int j = 0; j < 2; ++j) {
        int p = p0 + wc + j * 16 + lm;
        float gv = gate[(size_t)b * HW + p];
#pragma unroll
        for (int i = 0; i < 4; ++i)
#pragma unroll
            for (int r = 0; r < 4; ++r) {
                int o = o0 + wr + i * 16 + q * 4 + r;
                outp[((size_t)b * CCH + o) * HW + p] =
                    acc[0][i][j][r] * gv + acc[1][i][j][r];
            }
    }
}

// ---------------------------------------------------------------------------
extern "C" void kernel_launch(void* const* d_in, const int* in_sizes, int n_in,
                              void* d_out, int out_size, void* d_ws, size_t ws_size,
                              hipStream_t stream) {
    (void)in_sizes; (void)n_in; (void)out_size; (void)ws_size;
    const float* in1 = (const float*)d_in[0];
    const float* in2 = (const float*)d_in[1];
    const float* We  = (const float*)d_in[2];
    const float* gw  = (const float*)d_in[3];
    const float* W1  = (const float*)d_in[4];
    const float* W2  = (const float*)d_in[5];
    float* out = (float*)d_out;
    char* ws = (char*)d_ws;

    const size_t SB = (size_t)BATCH * CCH * HW * 2;    // 8 MB bf16 tensor
    const size_t WB = (size_t)CCH * 2 * CCH * 2;       // 256 KB
    const size_t EB = (size_t)CCH * CCH * 2;           // 128 KB (We16)
    const size_t VB = (size_t)BATCH * NM * 4;          // 64 KB

    size_t off = 0;
    auto alloc = [&](size_t bytes) {
        char* p = ws + off;
        off += (bytes + 255) & ~(size_t)255;
        return p;
    };
    short* W16_1 = (short*)alloc(WB);
    short* W16_2 = (short*)alloc(WB);
    short* We16  = (short*)alloc(EB);
    short* Xt16  = (short*)alloc(SB);   // in1^T (b,p,c)
    short* Qt16  = (short*)alloc(SB);   // in2^T (b,p,c)
    short* E16n  = (short*)alloc(SB);   // (b,n,d)
    short* eattT = (short*)alloc(SB);
    short* qattT = (short*)alloc(SB);
    short* X16   = (short*)alloc(SB);   // in1 (b,c,p) bf16
    short* Q16   = (short*)alloc(SB);   // in2 (b,c,p) bf16
    float* m1v   = (float*)alloc(VB);
    float* m2v   = (float*)alloc(VB);

    const int nW = CCH * 2 * CCH;
    const int nWe = CCH * CCH;

    k_cast<<<dim3(nW / 1024), 256, 0, stream>>>(W1, W16_1, nW);
    k_cast<<<dim3(nW / 1024), 256, 0, stream>>>(W2, W16_2, nW);
    k_cast<<<dim3(nWe / 1024), 256, 0, stream>>>(We, We16, nWe);
    k_prep<<<dim3(HW / 64, CCH / 64, 8), 256, 0, stream>>>(in1, in2, X16, Q16,
                                                           Xt16, Qt16);

    k_E_mfma<<<dim3(2, 32, BATCH), 256, 0, stream>>>(Xt16, We16, E16n);

    k_fused<<<dim3((HW / 128) * 8), 512, 0, stream>>>(E16n, Qt16, Q16, X16, gw,
                                                      eattT, qattT, m1v, m2v);

    k_final<<<dim3(64, 2, 8), 256, 0, stream>>>(W16_1, W16_2, eattT, qattT,
                                                Xt16, Qt16, m1v, m2v, out);
}

// Round 5
// 295.696 us; speedup vs baseline: 2.1079x; 1.0278x over previous
//
#include <hip/hip_runtime.h>
#include <cstdint>
#include <cstddef>

#define BATCH 4
#define CCH   256
#define HW    4096
#define NM    4096

typedef __attribute__((ext_vector_type(8))) short s16x8;
typedef __attribute__((ext_vector_type(4))) float f32x4;

__device__ __forceinline__ short f2bf(float f) {
    unsigned u = __float_as_uint(f);
    u += 0x7FFFu + ((u >> 16) & 1u);
    return (short)(u >> 16);
}
__device__ __forceinline__ float bf2f(short s) {
    return __uint_as_float(((unsigned)(unsigned short)s) << 16);
}

// async global -> LDS, 16B per lane. LDS dest is wave-uniform base + lane*16.
__device__ __forceinline__ void gload16(const void* g, void* l) {
    __builtin_amdgcn_global_load_lds(
        (const __attribute__((address_space(1))) unsigned int*)g,
        (__attribute__((address_space(3))) unsigned int*)l, 16, 0, 0);
}

// ---------------------------------------------------------------------------
// k_cast: fp32 -> bf16, same layout (weights only).
// ---------------------------------------------------------------------------
__global__ __launch_bounds__(256) void k_cast(const float* __restrict__ s,
                                              short* __restrict__ d, int n) {
    int i = (blockIdx.x * 256 + threadIdx.x) * 4;
    if (i + 3 < n) {
        float4 v = *(const float4*)&s[i];
        *(short4*)&d[i] = make_short4(f2bf(v.x), f2bf(v.y), f2bf(v.z), f2bf(v.w));
    }
}

// ---------------------------------------------------------------------------
// k_prep: one pass over in1/in2 producing direct bf16 (b,c,p) and transposed
// bf16 (b,p,c). grid (HW/64, CCH/64, 8): z = b*2+which.
// ---------------------------------------------------------------------------
__global__ __launch_bounds__(256) void k_prep(const float* __restrict__ in1,
                                              const float* __restrict__ in2,
                                              short* __restrict__ X16,
                                              short* __restrict__ Q16,
                                              short* __restrict__ Xt16,
                                              short* __restrict__ Qt16) {
    __shared__ short S[64][72];
    int t = threadIdx.x;
    int p0 = blockIdx.x * 64, c0 = blockIdx.y * 64;
    int z = blockIdx.z;
    int b = z >> 1, which = z & 1;
    const float* src = (which ? in2 : in1) + (size_t)b * CCH * HW;
    short* direct = (which ? Q16 : X16) + (size_t)b * CCH * HW;
    short* trans  = (which ? Qt16 : Xt16) + (size_t)b * HW * CCH;
    int tx = t & 15, ty = t >> 4;
#pragma unroll
    for (int i = 0; i < 4; ++i) {
        int c = ty + i * 16;
        float4 v = *(const float4*)&src[(size_t)(c0 + c) * HW + p0 + tx * 4];
        short4 h = make_short4(f2bf(v.x), f2bf(v.y), f2bf(v.z), f2bf(v.w));
        *(short4*)&direct[(size_t)(c0 + c) * HW + p0 + tx * 4] = h;
        S[tx * 4 + 0][c] = h.x;
        S[tx * 4 + 1][c] = h.y;
        S[tx * 4 + 2][c] = h.z;
        S[tx * 4 + 3][c] = h.w;
    }
    __syncthreads();
#pragma unroll
    for (int i = 0; i < 4; ++i) {
        int p = ty + i * 16;
        short4 v = *(const short4*)&S[p][tx * 4];
        *(short4*)&trans[(size_t)(p0 + p) * CCH + c0 + tx * 4] = v;
    }
}

// ---------------------------------------------------------------------------
// k_E_mfma: E16n[b,n,d] = bf16( sum_c Xt16[b,n,c] * We16[d,c] )
// TM=128(n), TN=128(d), BK=64, K=256. grid (2, 32, B), block 256.
// ---------------------------------------------------------------------------
__global__ __launch_bounds__(256) void k_E_mfma(const short* __restrict__ Xt16,
                                                const short* __restrict__ We16,
                                                short* __restrict__ E16n) {
    __shared__ short As[128 * 72];
    __shared__ short Bs[128 * 72];
    int t = threadIdx.x;
    int d0 = blockIdx.x * 128, n0 = blockIdx.y * 128, b = blockIdx.z;
    const short* Xb = Xt16 + (size_t)b * HW * CCH;
    short* Eb = E16n + (size_t)b * HW * CCH;
    int lm = t & 15, q = (t >> 4) & 3, w = t >> 6;
    int wr = (w >> 1) * 64, wc = (w & 1) * 64;
    f32x4 acc[4][4];
#pragma unroll
    for (int i = 0; i < 4; ++i)
#pragma unroll
        for (int j = 0; j < 4; ++j) acc[i][j] = (f32x4){0.f, 0.f, 0.f, 0.f};

    for (int k0 = 0; k0 < CCH; k0 += 64) {
#pragma unroll
        for (int u = 0; u < 4; ++u) {
            int chunk = t + u * 256;
            int row = chunk >> 3, off = (chunk & 7) * 8;
            *(float4*)&As[row * 72 + off] =
                *(const float4*)&Xb[(size_t)(n0 + row) * CCH + k0 + off];
            *(float4*)&Bs[row * 72 + off] =
                *(const float4*)&We16[(size_t)(d0 + row) * CCH + k0 + off];
        }
        __syncthreads();
#pragma unroll
        for (int kk = 0; kk < 2; ++kk) {
            s16x8 af[4], bfr[4];
#pragma unroll
            for (int i = 0; i < 4; ++i)
                af[i] = *(const s16x8*)&As[(wr + i * 16 + lm) * 72 + kk * 32 + q * 8];
#pragma unroll
            for (int j = 0; j < 4; ++j)
                bfr[j] = *(const s16x8*)&Bs[(wc + j * 16 + lm) * 72 + kk * 32 + q * 8];
#pragma unroll
            for (int i = 0; i < 4; ++i)
#pragma unroll
                for (int j = 0; j < 4; ++j)
                    acc[i][j] = __builtin_amdgcn_mfma_f32_16x16x32_bf16(
                        af[i], bfr[j], acc[i][j], 0, 0, 0);
        }
        __syncthreads();
    }
#pragma unroll
    for (int i = 0; i < 4; ++i)
#pragma unroll
        for (int r = 0; r < 4; ++r) {
            size_t base = (size_t)(n0 + wr + i * 16 + q * 4 + r) * CCH;
#pragma unroll
            for (int j = 0; j < 4; ++j)
                Eb[base + d0 + wc + j * 16 + lm] = f2bf(acc[i][j][r]);
        }
}

// ---------------------------------------------------------------------------
// k_fused v7: 128 rows/block, grid 256 (1 block/CU), 512 threads (8 waves).
// v6 post-mortem: global bf/vf loads latency-starved (~9 B/cyc/CU vs 128 KB
// per tile = the whole tile time). v7 hides the global stream:
//  - Ar rows in REGISTERS (wave owns 16 rows; af = 32 VGPR). No ArS.
//  - Ac tile staged to LDS via global_load_lds (fire-and-forget DMA) during
//    the PREVIOUS tile's PV phase. LDS linear dest + inverse-swizzled global
//    source + swizzled read (involution: byte ^= (col&7)<<4) for bank-minimal
//    ds_read_b128 of columns (512B stride would otherwise be a full conflict).
//  - V prefetched to regs at score start, consumed in PV (T14 split).
// Score: wave computes S[its 16 rows][all 128 cols] from af regs x AcS.
// Ps single-buffered; 2 barriers/tile. rsum is wave-local (exclusive rows).
// LDS: AcS 64K + Ps 67.6K + rs 0.5K + grs 4K = 137.7 KB.
// ---------------------------------------------------------------------------
__global__ __launch_bounds__(512, 2) void k_fused(const short* __restrict__ E16n,
                                                  const short* __restrict__ Qt16,
                                                  const short* __restrict__ Q16,
                                                  const short* __restrict__ X16,
                                                  const float* __restrict__ gw,
                                                  short* __restrict__ eattT,
                                                  short* __restrict__ qattT,
                                                  float* __restrict__ m1v,
                                                  float* __restrict__ m2v) {
    __shared__ short AcS[128 * 256];   // 64 KB, swizzled (see above)
    __shared__ short Ps[128 * 264];    // 67.6 KB (132 dw stride; mod-32 = 4)
    __shared__ float rs[128];          // rowsum (exclusive per-wave rows)
    __shared__ float grs[8 * 128];     // gate-dot cross-wave

    int t = threadIdx.x;
    int gid = blockIdx.x;
    int unit = gid & 7;
    int b = unit >> 1, which = unit & 1;
    int r0 = (gid >> 3) * 128;

    const short* Ar = (which ? Qt16 : E16n) + (size_t)b * HW * CCH;
    const short* Ac = (which ? E16n : Qt16) + (size_t)b * HW * CCH;
    const short* V  = (which ? X16  : Q16 ) + (size_t)b * CCH * HW;
    short* Out = (which ? qattT : eattT) + (size_t)b * HW * CCH;
    float* mdst = (which ? m2v : m1v) + (size_t)b * HW;

    int lm = t & 15, q = (t >> 4) & 3, w = t >> 6;   // w in [0,8)
    int lane = t & 63;
    int cq = w * 32;   // this wave's V-channel slice (32 of 256)

    // gate weights for this lane's 2 channels
    float gwv[2];
#pragma unroll
    for (int j = 0; j < 2; ++j) gwv[j] = gw[cq + j * 16 + lm];

    // ---- Ar fragments for this wave's 16 rows (registers, once)
    s16x8 af[8];
#pragma unroll
    for (int kk = 0; kk < 8; ++kk)
        af[kk] = *(const s16x8*)&Ar[(size_t)(r0 + w * 16 + lm) * CCH + kk * 32 + q * 8];

    // ---- prologue: stage Ac tile 0 into AcS (swizzled source, linear dest)
    {
        const char* AcB = (const char*)Ac;   // col0 = 0
#pragma unroll
        for (int c = 0; c < 8; ++c) {
            int Lb = (w * 8 + c) << 10;          // wave-uniform LDS byte base
            int L = Lb + lane * 16;
            int col = L >> 9;
            int soff = (col << 9) | ((L & 511) ^ ((col & 7) << 4));
            gload16(AcB + soff, (char*)AcS + Lb);
        }
    }
    __syncthreads();   // drains vmcnt: AcS(0) ready

    f32x4 oacc[8][2];
    float rsum[4];
#pragma unroll
    for (int i = 0; i < 8; ++i)
#pragma unroll
        for (int j = 0; j < 2; ++j) oacc[i][j] = (f32x4){0.f, 0.f, 0.f, 0.f};
#pragma unroll
    for (int r = 0; r < 4; ++r) rsum[r] = 0.f;

    for (int col0 = 0; col0 < NM; col0 += 128) {
        // ---- V prefetch for this tile's PV (lands during score)
        s16x8 vf[4][2];
#pragma unroll
        for (int km = 0; km < 4; ++km)
#pragma unroll
            for (int j = 0; j < 2; ++j)
                vf[km][j] = *(const s16x8*)&V[(size_t)(cq + j * 16 + lm) * HW +
                                              col0 + km * 32 + q * 8];

        // ---- score: S[wave's 16 rows][128 cols] = af(regs) . AcS(swizzled)
        f32x4 sacc[8];
#pragma unroll
        for (int j = 0; j < 8; ++j) sacc[j] = (f32x4){0.f, 0.f, 0.f, 0.f};
#pragma unroll
        for (int kk = 0; kk < 8; ++kk) {
            int swk = ((kk * 64 + q * 16) ^ ((lm & 7) << 4)) >> 1;   // shorts
            s16x8 bf[8];
#pragma unroll
            for (int j = 0; j < 8; ++j)
                bf[j] = *(const s16x8*)&AcS[(j * 16 + lm) * 256 + swk];
#pragma unroll
            for (int j = 0; j < 8; ++j)
                sacc[j] = __builtin_amdgcn_mfma_f32_16x16x32_bf16(
                    af[kk], bf[j], sacc[j], 0, 0, 0);
        }
        // ---- exp in registers; wave-local rowsum
#pragma unroll
        for (int j = 0; j < 8; ++j)
#pragma unroll
            for (int r = 0; r < 4; ++r) {
                float v = bf2f(f2bf(__expf(sacc[j][r])));
                rsum[r] += v;
                sacc[j][r] = v;
            }
        // ---- write P rows (safe: prior tile's Ps reads done at last barrier)
#pragma unroll
        for (int j = 0; j < 8; ++j)
#pragma unroll
            for (int r = 0; r < 4; ++r)
                Ps[(w * 16 + q * 4 + r) * 264 + j * 16 + lm] =
                    (short)(__float_as_uint(sacc[j][r]) >> 16);
        __syncthreads();   // A: Ps visible; all AcS reads of this tile done

        // ---- stage next Ac tile (async; flies during PV)
        if (col0 + 128 < NM) {
            const char* AcB = (const char*)(Ac + (size_t)(col0 + 128) * CCH);
#pragma unroll
            for (int c = 0; c < 8; ++c) {
                int Lb = (w * 8 + c) << 10;
                int L = Lb + lane * 16;
                int col = L >> 9;
                int soff = (col << 9) | ((L & 511) ^ ((col & 7) << 4));
                gload16(AcB + soff, (char*)AcS + Lb);
            }
        }

        // ---- PV: oacc += P[all 128 rows][tile] . V(prefetched regs)
#pragma unroll
        for (int km = 0; km < 4; ++km) {
            s16x8 pf[8];
#pragma unroll
            for (int i = 0; i < 8; ++i)
                pf[i] = *(const s16x8*)&Ps[(i * 16 + lm) * 264 + km * 32 + q * 8];
#pragma unroll
            for (int i = 0; i < 8; ++i)
#pragma unroll
                for (int j = 0; j < 2; ++j)
                    oacc[i][j] = __builtin_amdgcn_mfma_f32_16x16x32_bf16(
                        pf[i], vf[km][j], oacc[i][j], 0, 0, 0);
        }
        __syncthreads();   // Z: drains vmcnt -> AcS(t+1) complete; Ps reads done
    }

    // ---- rowsum: reduce over lm lanes (wave owns its 16 rows exclusively)
#pragma unroll
    for (int r = 0; r < 4; ++r) {
        float s = rsum[r];
        s += __shfl_xor(s, 1, 64);
        s += __shfl_xor(s, 2, 64);
        s += __shfl_xor(s, 4, 64);
        s += __shfl_xor(s, 8, 64);
        if (lm == 0) rs[w * 16 + q * 4 + r] = s;
    }
    __syncthreads();

    // ---- normalize, store bf16 output, accumulate gate dot-product
    float gacc[8][4];
#pragma unroll
    for (int i = 0; i < 8; ++i)
#pragma unroll
        for (int r = 0; r < 4; ++r) {
            int row = i * 16 + q * 4 + r;
            float inv = 1.f / rs[row];
            size_t base = (size_t)(r0 + row) * CCH;
            float ga = 0.f;
#pragma unroll
            for (int j = 0; j < 2; ++j) {
                short h = f2bf(oacc[i][j][r] * inv);
                Out[base + cq + j * 16 + lm] = h;
                ga = fmaf(bf2f(h), gwv[j], ga);
            }
            gacc[i][r] = ga;
        }
    // gate: reduce over lm, then across waves, sigmoid
#pragma unroll
    for (int i = 0; i < 8; ++i)
#pragma unroll
        for (int r = 0; r < 4; ++r) {
            float s = gacc[i][r];
            s += __shfl_xor(s, 1, 64);
            s += __shfl_xor(s, 2, 64);
            s += __shfl_xor(s, 4, 64);
            s += __shfl_xor(s, 8, 64);
            if (lm == 0) grs[w * 128 + i * 16 + q * 4 + r] = s;
        }
    __syncthreads();
    if (t < 128) {
        float g = 0.f;
#pragma unroll
        for (int ww = 0; ww < 8; ++ww) g += grs[ww * 128 + t];
        mdst[r0 + t] = 1.f / (1.f + __expf(-g));
    }
}

// ---------------------------------------------------------------------------
// k_final (merged): half = blockIdx.z>>2 selects (W1,eattT,Xt16,m1,out1) vs
// (W2,qattT,Qt16,m2,out2). TM=128(o), TN=64(p), BK=32, two K=256 phases.
// grid (64, 2, 8), block 256.
// ---------------------------------------------------------------------------
__global__ __launch_bounds__(256) void k_final(const short* __restrict__ W16_1,
                                               const short* __restrict__ W16_2,
                                               const short* __restrict__ eattT,
                                               const short* __restrict__ qattT,
                                               const short* __restrict__ Xt16,
                                               const short* __restrict__ Qt16,
                                               const float* __restrict__ m1v,
                                               const float* __restrict__ m2v,
                                               float* __restrict__ outbase) {
    __shared__ short As[128 * 40];
    __shared__ short Bs[64 * 40];
    int t = threadIdx.x;
    int zz = blockIdx.z;
    int half = zz >> 2, b = zz & 3;
    const short* W16 = half ? W16_2 : W16_1;
    const short* attT = (half ? qattT : eattT);
    const short* inT  = (half ? Qt16 : Xt16);
    const float* gate = half ? m2v : m1v;
    float* outp = outbase + (size_t)half * BATCH * CCH * HW;
    int p0 = blockIdx.x * 64, o0 = blockIdx.y * 128;
    const short* Tb0 = attT + (size_t)b * HW * CCH;
    const short* Tb1 = inT + (size_t)b * HW * CCH;
    int lm = t & 15, q = (t >> 4) & 3, w = t >> 6;
    int wr = (w >> 1) * 64, wc = (w & 1) * 32;
    f32x4 acc[2][4][2];
#pragma unroll
    for (int ph = 0; ph < 2; ++ph)
#pragma unroll
        for (int i = 0; i < 4; ++i)
#pragma unroll
            for (int j = 0; j < 2; ++j) acc[ph][i][j] = (f32x4){0.f, 0.f, 0.f, 0.f};

    int brow = t >> 2, boff = (t & 3) * 8;
    for (int ph = 0; ph < 2; ++ph) {
        const short* Tb = ph ? Tb1 : Tb0;
        for (int k0 = 0; k0 < CCH; k0 += 32) {
#pragma unroll
            for (int u = 0; u < 2; ++u) {
                int chunk = t + u * 256;
                int row = chunk >> 2, off = (chunk & 3) * 8;
                *(float4*)&As[row * 40 + off] =
                    *(const float4*)&W16[(size_t)(o0 + row) * 512 + ph * 256 + k0 + off];
            }
            *(float4*)&Bs[brow * 40 + boff] =
                *(const float4*)&Tb[(size_t)(p0 + brow) * CCH + k0 + boff];
            __syncthreads();
            s16x8 af[4], bfr[2];
#pragma unroll
            for (int i = 0; i < 4; ++i)
                af[i] = *(const s16x8*)&As[(wr + i * 16 + lm) * 40 + q * 8];
#pragma unroll
            for (int j = 0; j < 2; ++j)
                bfr[j] = *(const s16x8*)&Bs[(wc + j * 16 + lm) * 40 + q * 8];
#pragma unroll
            for (int i = 0; i < 4; ++i)
#pragma unroll
                for (int j = 0; j < 2; ++j)
                    acc[ph][i][j] = __builtin_amdgcn_mfma_f32_16x16x32_bf16(
                        af[i], bfr[j], acc[ph][i][j], 0, 0, 0);
            __syncthreads();
        }
    }
#pragma unroll
    for (int j = 0; j < 2; ++j) {
        int p = p0 + wc + j * 16 + lm;
        float gv = gate[(size_t)b * HW + p];
#pragma unroll
        for (int i = 0; i < 4; ++i)
#pragma unroll
            for (int r = 0; r < 4; ++r) {
                int o = o0 + wr + i * 16 + q * 4 + r;
                outp[((size_t)b * CCH + o) * HW + p] =
                    acc[0][i][j][r] * gv + acc[1][i][j][r];
            }
    }
}

// ---------------------------------------------------------------------------
extern "C" void kernel_launch(void* const* d_in, const int* in_sizes, int n_in,
                              void* d_out, int out_size, void* d_ws, size_t ws_size,
                              hipStream_t stream) {
    (void)in_sizes; (void)n_in; (void)out_size; (void)ws_size;
    const float* in1 = (const float*)d_in[0];
    const float* in2 = (const float*)d_in[1];
    const float* We  = (const float*)d_in[2];
    const float* gw  = (const float*)d_in[3];
    const float* W1  = (const float*)d_in[4];
    const float* W2  = (const float*)d_in[5];
    float* out = (float*)d_out;
    char* ws = (char*)d_ws;

    const size_t SB = (size_t)BATCH * CCH * HW * 2;    // 8 MB bf16 tensor
    const size_t WB = (size_t)CCH * 2 * CCH * 2;       // 256 KB
    const size_t EB = (size_t)CCH * CCH * 2;           // 128 KB (We16)
    const size_t VB = (size_t)BATCH * NM * 4;          // 64 KB

    size_t off = 0;
    auto alloc = [&](size_t bytes) {
        char* p = ws + off;
        off += (bytes + 255) & ~(size_t)255;
        return p;
    };
    short* W16_1 = (short*)alloc(WB);
    short* W16_2 = (short*)alloc(WB);
    short* We16  = (short*)alloc(EB);
    short* Xt16  = (short*)alloc(SB);   // in1^T (b,p,c)
    short* Qt16  = (short*)alloc(SB);   // in2^T (b,p,c)
    short* E16n  = (short*)alloc(SB);   // (b,n,d)
    short* eattT = (short*)alloc(SB);
    short* qattT = (short*)alloc(SB);
    short* X16   = (short*)alloc(SB);   // in1 (b,c,p) bf16
    short* Q16   = (short*)alloc(SB);   // in2 (b,c,p) bf16
    float* m1v   = (float*)alloc(VB);
    float* m2v   = (float*)alloc(VB);

    const int nW = CCH * 2 * CCH;
    const int nWe = CCH * CCH;

    k_cast<<<dim3(nW / 1024), 256, 0, stream>>>(W1, W16_1, nW);
    k_cast<<<dim3(nW / 1024), 256, 0, stream>>>(W2, W16_2, nW);
    k_cast<<<dim3(nWe / 1024), 256, 0, stream>>>(We, We16, nWe);
    k_prep<<<dim3(HW / 64, CCH / 64, 8), 256, 0, stream>>>(in1, in2, X16, Q16,
                                                           Xt16, Qt16);

    k_E_mfma<<<dim3(2, 32, BATCH), 256, 0, stream>>>(Xt16, We16, E16n);

    k_fused<<<dim3((HW / 128) * 8), 512, 0, stream>>>(E16n, Qt16, Q16, X16, gw,
                                                      eattT, qattT, m1v, m2v);

    k_final<<<dim3(64, 2, 8), 256, 0, stream>>>(W16_1, W16_2, eattT, qattT,
                                                Xt16, Qt16, m1v, m2v, out);
}